// Round 6
// baseline (1031.351 us; speedup 1.0000x reference)
//
#include <hip/hip_runtime.h>

// NeuralIF GraphNet: 3 layers x (lower GraphNet, upper GraphNet).
// R1: bucketed edge lists + LDS-bin aggregation (no scattered global atomics).
// R4: no __threadfence / done-counter in hot kernels.
// R5: agg+node fused; inline global MLP in edge kernel wave 0.
// R6: edge MLP processes 4 edges/thread -> the 18 s_load weight fetches per
// hidden unit are amortized over 4x18 FMAs (was lgkm-stall-bound: true VALU
// duty ~14%, 60us vs 9us ideal). 256 blocks x 512 threads, one prologue round.

typedef unsigned int u32;

#define NB_SHIFT 9
#define NB_SIZE 512
#define RSTRIDE 1104  // per-GraphNet region: ebins[64] nbins[64*16] pad
#define EG_BLOCKS 256

__device__ __forceinline__ float wave_sum(float v) {
#pragma unroll
    for (int off = 32; off > 0; off >>= 1) v += __shfl_down(v, off, 64);
    return v;
}

// ---------------- bucketed-list build (once per call) ----------------

__global__ __launch_bounds__(256) void hist_kernel(
    const int* __restrict__ lr, const int* __restrict__ ur,
    u32* __restrict__ hist, int E, int B) {
    __shared__ u32 h[256];
    const int t = threadIdx.x;
    if (t < B) h[t] = 0;
    __syncthreads();
    const int s = blockIdx.y;
    const int* rows = s ? ur : lr;
    for (int i = blockIdx.x * 256 + t; i < E; i += gridDim.x * 256)
        atomicAdd(&h[rows[i] >> NB_SHIFT], 1u);
    __syncthreads();
    if (t < B && h[t]) atomicAdd(&hist[s * B + t], h[t]);
}

__global__ void scan_kernel(const u32* __restrict__ hist, u32* __restrict__ offs,
                            u32* __restrict__ cur, int B) {
    if (threadIdx.x == 0) {
        for (int s = 0; s < 2; ++s) {
            u32 acc = 0;
            for (int b = 0; b < B; ++b) {
                offs[s * (B + 1) + b] = acc;
                cur[s * B + b] = acc;
                acc += hist[s * B + b];
            }
            offs[s * (B + 1) + B] = acc;
        }
    }
}

#define SCHUNK 4096
__global__ __launch_bounds__(256) void scatter_kernel(
    const int* __restrict__ lr, const int* __restrict__ ur,
    u32* __restrict__ cur, u32* __restrict__ list, int E, int B) {
    __shared__ u32 lcnt[256], lbase[256];
    const int t = threadIdx.x;
    const int s = blockIdx.y;
    const int* rows = s ? ur : lr;
    u32* mylist = list + (size_t)s * E;
    if (t < B) lcnt[t] = 0;
    __syncthreads();
    const int base_e = blockIdx.x * SCHUNK;
#pragma unroll
    for (int k = 0; k < SCHUNK / 256; ++k) {
        const int e = base_e + k * 256 + t;
        if (e < E) atomicAdd(&lcnt[rows[e] >> NB_SHIFT], 1u);
    }
    __syncthreads();
    if (t < B) {
        const u32 c = lcnt[t];
        lbase[t] = c ? atomicAdd(&cur[s * B + t], c) : 0u;
        lcnt[t] = 0;
    }
    __syncthreads();
#pragma unroll
    for (int k = 0; k < SCHUNK / 256; ++k) {
        const int e = base_e + k * 256 + t;
        if (e < E) {
            const int b = rows[e] >> NB_SHIFT;
            const u32 pos = lbase[b] + atomicAdd(&lcnt[b], 1u);
            mylist[pos] = (u32)e;
        }
    }
}

// ---------------- edge MLP (+ inline global MLP in wave 0) ----------------
// 4 edges per thread: weight s_loads per hidden unit feed 4x FMAs.

template <bool SKIP, bool GAGG, bool VALS, bool STORE, bool GCOMP>
__global__ __launch_bounds__(512, 2) void edge_kernel(
    const float4* __restrict__ xf,       // node features (N,8) as float4 pairs
    const int* __restrict__ rows, const int* __restrict__ cols,
    const float* __restrict__ eprev,     // previous edge embedding (E)
    const float* __restrict__ skipattr,  // original attr (skip col), if SKIP
    const float* __restrict__ W1,        // 26x32 slice (row-major k,j)
    const float* __restrict__ b1,        // 32
    const float* __restrict__ W2,        // 32
    const float* __restrict__ b2,        // 1
    const float* __restrict__ gprev,     // gslot[j-1] (GCOMP) / gslot[0]=0
    float* __restrict__ gout,            // gslot[j] (GCOMP: block0 writes)
    const float* __restrict__ pebins,    // prev region e-mean bins (GCOMP)
    const float* __restrict__ pnbins,    // prev region n-mean bins (GCOMP)
    const float* __restrict__ gW1, const float* __restrict__ gb1,
    const float* __restrict__ gW2, const float* __restrict__ gb2,
    float* __restrict__ ebins,           // this region's e-mean bins (GAGG)
    float* __restrict__ e_out,           // edge emb store (STORE)
    float* __restrict__ vals_out,        // final output segment (VALS)
    int E, int N, float inv_E) {
    __shared__ float gsh[8];
    __shared__ float biasE[32];
    __shared__ float wpart[8];
    const int t = threadIdx.x;
    if constexpr (GCOMP) {
        if (t < 64) {  // wave 0: g = gMLP(n_mean, e_mean, g_prev)
            float nb[8];
#pragma unroll
            for (int q = 0; q < 8; ++q) nb[q] = pnbins[t * 16 + q];
            const float eb = pebins[t];
            float gin[17];
#pragma unroll
            for (int q = 0; q < 8; ++q) {
                const float s = wave_sum(nb[q]);
                gin[q] = __shfl(s, 0, 64) / (float)N;
            }
            const float es = wave_sum(eb);
            gin[8] = __shfl(es, 0, 64) * inv_E;
#pragma unroll
            for (int k = 0; k < 8; ++k) gin[9 + k] = gprev[k];
            float hv = 0.0f;
            if (t < 32) {
                hv = gb1[t];
#pragma unroll
                for (int k = 0; k < 17; ++k)
                    hv = fmaf(gin[k], gW1[k * 32 + t], hv);
                hv = fmaxf(hv, 0.0f);
            }
#pragma unroll
            for (int q = 0; q < 8; ++q) {
                const float c = (t < 32) ? hv * gW2[t * 8 + q] : 0.0f;
                const float s = wave_sum(c);
                if (t == 0) {
                    const float gv = gb2[q] + s;
                    gsh[q] = gv;
                    if (blockIdx.x == 0) gout[q] = gv;
                }
            }
        }
    } else {
        if (t < 8) gsh[t] = gprev[t];
    }
    __syncthreads();
    if (t < 32) {
        // fold uniform global contribution + b1 into per-pass bias
        float v = b1[t];
#pragma unroll
        for (int k = 0; k < 8; ++k) v = fmaf(gsh[k], W1[k * 32 + t], v);
        biasE[t] = v;
    }
    __syncthreads();

    const float* __restrict__ Wk = W1 + 8 * 32;  // rows 8..25
    const float b2v = b2[0];
    float accsum = 0.0f;
    const int stride = gridDim.x * 512 * 4;
    for (int e0 = (blockIdx.x * 512 + t) * 4; e0 < E; e0 += stride) {
        const int4 r4 = *(const int4*)(rows + e0);
        const int4 c4 = *(const int4*)(cols + e0);
        const float4 ep4 = *(const float4*)(eprev + e0);
        float4 sk4 = make_float4(0.f, 0.f, 0.f, 0.f);
        if constexpr (SKIP) sk4 = *(const float4*)(skipattr + e0);

        float in[4][18];
        {
            const int rr[4] = {r4.x, r4.y, r4.z, r4.w};
            const int cc[4] = {c4.x, c4.y, c4.z, c4.w};
            const float ee[4] = {ep4.x, ep4.y, ep4.z, ep4.w};
            const float ss[4] = {sk4.x, sk4.y, sk4.z, sk4.w};
#pragma unroll
            for (int u = 0; u < 4; ++u) {
                const float4 a0 = xf[2 * rr[u]], a1 = xf[2 * rr[u] + 1];
                const float4 bb0 = xf[2 * cc[u]], bb1 = xf[2 * cc[u] + 1];
                in[u][0] = a0.x; in[u][1] = a0.y; in[u][2] = a0.z; in[u][3] = a0.w;
                in[u][4] = a1.x; in[u][5] = a1.y; in[u][6] = a1.z; in[u][7] = a1.w;
                in[u][8] = bb0.x; in[u][9] = bb0.y; in[u][10] = bb0.z; in[u][11] = bb0.w;
                in[u][12] = bb1.x; in[u][13] = bb1.y; in[u][14] = bb1.z; in[u][15] = bb1.w;
                in[u][16] = ee[u]; in[u][17] = ss[u];
            }
        }
        float out[4] = {b2v, b2v, b2v, b2v};
#pragma unroll
        for (int j = 0; j < 32; ++j) {
            const float bj = biasE[j];
            float h0 = bj, h1 = bj, h2 = bj, h3 = bj;
#pragma unroll
            for (int k = 0; k < 18; ++k) {
                const float w = Wk[k * 32 + j];
                h0 = fmaf(in[0][k], w, h0);
                h1 = fmaf(in[1][k], w, h1);
                h2 = fmaf(in[2][k], w, h2);
                h3 = fmaf(in[3][k], w, h3);
            }
            const float w2j = W2[j];
            out[0] = fmaf(fmaxf(h0, 0.f), w2j, out[0]);
            out[1] = fmaf(fmaxf(h1, 0.f), w2j, out[1]);
            out[2] = fmaf(fmaxf(h2, 0.f), w2j, out[2]);
            out[3] = fmaf(fmaxf(h3, 0.f), w2j, out[3]);
        }
        if constexpr (STORE)
            *(float4*)(e_out + e0) = make_float4(out[0], out[1], out[2], out[3]);
        if constexpr (VALS) {
            float4 v;
            v.x = (r4.x == c4.x) ? expf(out[0]) : out[0];
            v.y = (r4.y == c4.y) ? expf(out[1]) : out[1];
            v.z = (r4.z == c4.z) ? expf(out[2]) : out[2];
            v.w = (r4.w == c4.w) ? expf(out[3]) : out[3];
            *(float4*)(vals_out + e0) = v;
        }
        if constexpr (GAGG) accsum += out[0] + out[1] + out[2] + out[3];
    }
    if constexpr (GAGG) {
        const float s = wave_sum(accsum);
        if ((t & 63) == 0) wpart[t >> 6] = s;
        __syncthreads();
        if (t == 0) {
            float a = 0.0f;
#pragma unroll
            for (int w = 0; w < 8; ++w) a += wpart[w];
            atomicAdd(&ebins[blockIdx.x & 63], a);
        }
    }
}

// ------- fused aggregation + node MLP: one block owns one bucket -------

template <bool COUNT, bool STORE_N>
__global__ __launch_bounds__(1024) void aggnode_kernel(
    const u32* __restrict__ list, const u32* __restrict__ offs,
    const int* __restrict__ rows, const float* __restrict__ e_emb,
    const float4* __restrict__ xf,  // node features: x (lower) or l_n (upper)
    float* __restrict__ cntf,       // per-node degree (write if COUNT else read)
    const float* __restrict__ g,    // gslot[j] (materialized)
    const float* __restrict__ nW1, const float* __restrict__ nb1,
    const float* __restrict__ nW2, const float* __restrict__ nb2,
    float* __restrict__ n_out,  // l_n (8N) if STORE_N
    float* __restrict__ nbins,  // 64 x 16 n-mean partial bins
    int N) {
    __shared__ float sbin[NB_SIZE];
    __shared__ float cbin[NB_SIZE];
    __shared__ float biasN[32];
    __shared__ float npart[8][8];
    const int t = threadIdx.x;
    if (t < NB_SIZE) {
        sbin[t] = 0.0f;
        if constexpr (COUNT) cbin[t] = 0.0f;
    }
    if (t >= NB_SIZE && t < NB_SIZE + 32) {
        const int j = t - NB_SIZE;
        float v = nb1[j];
#pragma unroll
        for (int k = 0; k < 8; ++k) v = fmaf(g[k], nW1[k * 32 + j], v);
        biasN[j] = v;
    }
    __syncthreads();
    const int b = blockIdx.x;
    const u32 beg = offs[b], end = offs[b + 1];
    for (u32 i = beg + t; i < end; i += 1024) {
        const u32 eid = list[i];
        const float v = e_emb[eid];
        const int r = rows[eid];
        atomicAdd(&sbin[r & (NB_SIZE - 1)], v);
        if constexpr (COUNT) atomicAdd(&cbin[r & (NB_SIZE - 1)], 1.0f);
    }
    __syncthreads();

    const int n0 = b << NB_SHIFT;
    float o[8];
    const bool active = (t < NB_SIZE) && (n0 + t < N);
    if (t < NB_SIZE) {
        const int n = n0 + t;
        const int idx = active ? n : (N - 1);
        float cntv;
        if constexpr (COUNT) {
            cntv = cbin[t];
            if (active) cntf[n] = cntv;
        } else {
            cntv = cntf[idx];
        }
        const float agg = sbin[t] / fmaxf(cntv, 1.0f);
        const float4 x0 = xf[2 * idx], x1 = xf[2 * idx + 1];
        float in[9] = {x0.x, x0.y, x0.z, x0.w, x1.x, x1.y, x1.z, x1.w, agg};
        float h[32];
#pragma unroll
        for (int j = 0; j < 8; ++j) {
            const float4 bb = reinterpret_cast<const float4*>(biasN)[j];
            h[4 * j + 0] = bb.x; h[4 * j + 1] = bb.y;
            h[4 * j + 2] = bb.z; h[4 * j + 3] = bb.w;
        }
        const float* __restrict__ Wk = nW1 + 8 * 32;
#pragma unroll
        for (int k = 0; k < 9; ++k) {
            const float v = in[k];
#pragma unroll
            for (int j = 0; j < 32; ++j) h[j] = fmaf(v, Wk[k * 32 + j], h[j]);
        }
#pragma unroll
        for (int q = 0; q < 8; ++q) o[q] = nb2[q];
#pragma unroll
        for (int j = 0; j < 32; ++j) {
            const float hv = fmaxf(h[j], 0.0f);
#pragma unroll
            for (int q = 0; q < 8; ++q) o[q] = fmaf(hv, nW2[j * 8 + q], o[q]);
        }
        if constexpr (STORE_N) {
            if (active) {
                reinterpret_cast<float4*>(n_out)[2 * n] =
                    make_float4(o[0], o[1], o[2], o[3]);
                reinterpret_cast<float4*>(n_out)[2 * n + 1] =
                    make_float4(o[4], o[5], o[6], o[7]);
            }
        }
#pragma unroll
        for (int q = 0; q < 8; ++q) {
            const float s = wave_sum(active ? o[q] : 0.0f);
            if ((t & 63) == 0) npart[t >> 6][q] = s;
        }
    }
    __syncthreads();
    if (t < 8) {
        float a = 0.0f;
#pragma unroll
        for (int w = 0; w < 8; ++w) a += npart[w][t];
        atomicAdd(&nbins[(b & 63) * 16 + t], a);
    }
}

extern "C" void kernel_launch(void* const* d_in, const int* in_sizes, int n_in,
                              void* d_out, int out_size, void* d_ws,
                              size_t ws_size, hipStream_t stream) {
    const float* x = (const float*)d_in[0];
    const int* l_ei = (const int*)d_in[1];
    const int* u_ei = (const int*)d_in[2];
    const float* l_attr = (const float*)d_in[3];
    const float* u_attr = (const float*)d_in[4];
    const float* eW1 = (const float*)d_in[5];
    const float* eb1 = (const float*)d_in[6];
    const float* eW2 = (const float*)d_in[7];
    const float* eb2 = (const float*)d_in[8];
    const float* nW1 = (const float*)d_in[9];
    const float* nb1 = (const float*)d_in[10];
    const float* nW2 = (const float*)d_in[11];
    const float* nb2 = (const float*)d_in[12];
    const float* gW1 = (const float*)d_in[13];
    const float* gb1 = (const float*)d_in[14];
    const float* gW2 = (const float*)d_in[15];
    const float* gb2 = (const float*)d_in[16];

    const int E = in_sizes[3];      // 1,100,000
    const int N = in_sizes[0] / 8;  // 100,000
    const int B = (N + NB_SIZE - 1) >> NB_SHIFT;  // 196 buckets

    // workspace layout (floats)
    float* ws = (float*)d_ws;
    float* l_e = ws;                      // E
    float* u_e = l_e + E;                 // E
    float* l_n = u_e + E;                 // 8N (float4-aligned)
    float* cnt_l = l_n + (size_t)8 * N;   // N (float degree)
    float* cnt_u = cnt_l + N;             // N
    float* gslot = cnt_u + N;             // 7 x 8 (slot j = g used by GNet j)
    u32* hist = (u32*)(gslot + 56);       // 2B
    float* dyn_all = (float*)(hist + 2 * B);    // 5 * RSTRIDE
    u32* offs = (u32*)(dyn_all + 5 * RSTRIDE);  // 2(B+1)
    u32* cur = offs + 2 * (B + 1);        // 2B
    u32* list = cur + 2 * B;              // 2E (lower | upper)

    const int* lr = l_ei;
    const int* lc = l_ei + E;
    const int* ur = u_ei;
    const int* uc = u_ei + E;
    const int sg = (E + SCHUNK - 1) / SCHUNK;
    const float invE = 1.0f / (float)E;
    float* outL = (float*)d_out;
    float* outU = outL + E;
    const u32* offs_l = offs;
    const u32* offs_u = offs + (B + 1);
    const u32* list_l = list;
    const u32* list_u = list + E;

    // one memset: gslots + hist + all 5 bin regions
    hipMemsetAsync(gslot, 0, (size_t)(56 + 2 * B + 5 * RSTRIDE) * sizeof(float),
                   stream);
    hist_kernel<<<dim3(128, 2), 256, 0, stream>>>(lr, ur, hist, E, B);
    scan_kernel<<<1, 64, 0, stream>>>(hist, offs, cur, B);
    scatter_kernel<<<dim3(sg, 2), 256, 0, stream>>>(lr, ur, cur, list, E, B);

    // weight-slice per GraphNet j: lower i -> i, upper i -> 3+i
    const size_t wsl[6] = {0, 3, 1, 4, 2, 5};

    for (int j = 0; j < 6; ++j) {
        const bool lower = !(j & 1);
        const size_t sl = wsl[j];
        float* ebins = dyn_all + (size_t)(j <= 4 ? j : 4) * RSTRIDE;
        float* nbins = ebins + 64;
        const float* pe = (j >= 1) ? dyn_all + (size_t)(j - 1) * RSTRIDE : nullptr;
        const float* pn = (j >= 1) ? pe + 64 : nullptr;
        const size_t psl = (j >= 1) ? wsl[j - 1] : 0;
        const float4* exf = (const float4*)(lower ? x : l_n);
        const int* rows = lower ? lr : ur;
        const int* cols = lower ? lc : uc;
        const float* eprev = (j == 0) ? l_attr
                             : (j == 1) ? u_attr
                             : (lower ? l_e : u_e);
        float* e_out = lower ? l_e : u_e;
        const float* gprev = gslot + (size_t)(j >= 1 ? j - 1 : 0) * 8;
        float* gout = gslot + (size_t)j * 8;

#define EDGE_ARGS                                                             \
    exf, rows, cols, eprev, l_attr, eW1 + sl * 832, eb1 + sl * 32,            \
        eW2 + sl * 32, eb2 + sl, gprev, gout, pe, pn, gW1 + psl * 544,        \
        gb1 + psl * 32, gW2 + psl * 256, gb2 + psl * 8, ebins,                \
        e_out, (j == 4) ? outL : outU, E, N, invE

        switch (j) {  // SKIP, GAGG, VALS, STORE, GCOMP
            case 0: edge_kernel<false, true, false, true, false>
                        <<<EG_BLOCKS, 512, 0, stream>>>(EDGE_ARGS); break;
            case 1: edge_kernel<false, true, false, true, true>
                        <<<EG_BLOCKS, 512, 0, stream>>>(EDGE_ARGS); break;
            case 2: edge_kernel<true, true, false, true, true>
                        <<<EG_BLOCKS, 512, 0, stream>>>(EDGE_ARGS); break;
            case 3: edge_kernel<false, true, false, true, true>
                        <<<EG_BLOCKS, 512, 0, stream>>>(EDGE_ARGS); break;
            case 4: edge_kernel<true, true, true, true, true>
                        <<<EG_BLOCKS, 512, 0, stream>>>(EDGE_ARGS); break;
            case 5: edge_kernel<false, false, true, false, true>
                        <<<EG_BLOCKS, 512, 0, stream>>>(EDGE_ARGS); break;
        }
#undef EDGE_ARGS

        if (j == 5) break;  // final upper GraphNet: edge output only

        const u32* alist = lower ? list_l : list_u;
        const u32* aoffs = lower ? offs_l : offs_u;
        float* cntf = lower ? cnt_l : cnt_u;
        const float4* nxf = (const float4*)(lower ? x : l_n);

#define AGG_ARGS                                                              \
    alist, aoffs, rows, e_out, nxf, cntf, gslot + (size_t)j * 8,              \
        nW1 + sl * 544, nb1 + sl * 32, nW2 + sl * 256, nb2 + sl * 8, l_n,     \
        nbins, N

        switch (j) {  // COUNT, STORE_N
            case 0: aggnode_kernel<true, true>
                        <<<B, 1024, 0, stream>>>(AGG_ARGS); break;
            case 1: aggnode_kernel<true, false>
                        <<<B, 1024, 0, stream>>>(AGG_ARGS); break;
            case 2: aggnode_kernel<false, true>
                        <<<B, 1024, 0, stream>>>(AGG_ARGS); break;
            case 3: aggnode_kernel<false, false>
                        <<<B, 1024, 0, stream>>>(AGG_ARGS); break;
            case 4: aggnode_kernel<false, true>
                        <<<B, 1024, 0, stream>>>(AGG_ARGS); break;
        }
#undef AGG_ARGS
    }
}

// Round 7
// 547.601 us; speedup vs baseline: 1.8834x; 1.8834x over previous
//
#include <hip/hip_runtime.h>

// NeuralIF GraphNet: 3 layers x (lower GraphNet, upper GraphNet).
// R1: bucketed edge lists + LDS-bin aggregation (no scattered global atomics).
// R4: no __threadfence / done-counter in hot kernels.
// R5: agg+node fused; inline global MLP in edge kernel wave 0.
// R6 FAILED: 4 edges/thread spilled in[4][18] to scratch (VGPR 84, 41ms dispatch).
// R7: edge kernel reverted to R4's proven one-edge-per-thread shape (VGPR 28,
// 4297 blocks -> full occupancy; R5's 1024-block grid capped occupancy at 50%).
// Keeps fused aggnode + inline GCOMP. scan_kernel parallelized (was 1 thread
// doing ~400 serialized dependent global round-trips).

typedef unsigned int u32;

#define NB_SHIFT 9
#define NB_SIZE 512
#define RSTRIDE 1104  // per-GraphNet region: ebins[64] nbins[64*16] pad

__device__ __forceinline__ float wave_sum(float v) {
#pragma unroll
    for (int off = 32; off > 0; off >>= 1) v += __shfl_down(v, off, 64);
    return v;
}

// ---------------- bucketed-list build (once per call) ----------------

__global__ __launch_bounds__(256) void hist_kernel(
    const int* __restrict__ lr, const int* __restrict__ ur,
    u32* __restrict__ hist, int E, int B) {
    __shared__ u32 h[256];
    const int t = threadIdx.x;
    if (t < B) h[t] = 0;
    __syncthreads();
    const int s = blockIdx.y;
    const int* rows = s ? ur : lr;
    for (int i = blockIdx.x * 256 + t; i < E; i += gridDim.x * 256)
        atomicAdd(&h[rows[i] >> NB_SHIFT], 1u);
    __syncthreads();
    if (t < B && h[t]) atomicAdd(&hist[s * B + t], h[t]);
}

// parallel exclusive scan of both segments (B <= 256), one block
__global__ __launch_bounds__(256) void scan_kernel(
    const u32* __restrict__ hist, u32* __restrict__ offs,
    u32* __restrict__ cur, int B) {
    __shared__ u32 sh[256];
    const int t = threadIdx.x;
    for (int s = 0; s < 2; ++s) {
        const u32 v = (t < B) ? hist[s * B + t] : 0u;
        sh[t] = v;
        __syncthreads();
#pragma unroll
        for (int off = 1; off < 256; off <<= 1) {
            const u32 add = (t >= off) ? sh[t - off] : 0u;
            __syncthreads();
            sh[t] += add;
            __syncthreads();
        }
        const u32 exc = sh[t] - v;
        if (t < B) {
            offs[s * (B + 1) + t] = exc;
            cur[s * B + t] = exc;
        }
        if (t == 255) offs[s * (B + 1) + B] = sh[255];
        __syncthreads();
    }
}

#define SCHUNK 4096
__global__ __launch_bounds__(256) void scatter_kernel(
    const int* __restrict__ lr, const int* __restrict__ ur,
    u32* __restrict__ cur, u32* __restrict__ list, int E, int B) {
    __shared__ u32 lcnt[256], lbase[256];
    const int t = threadIdx.x;
    const int s = blockIdx.y;
    const int* rows = s ? ur : lr;
    u32* mylist = list + (size_t)s * E;
    if (t < B) lcnt[t] = 0;
    __syncthreads();
    const int base_e = blockIdx.x * SCHUNK;
#pragma unroll
    for (int k = 0; k < SCHUNK / 256; ++k) {
        const int e = base_e + k * 256 + t;
        if (e < E) atomicAdd(&lcnt[rows[e] >> NB_SHIFT], 1u);
    }
    __syncthreads();
    if (t < B) {
        const u32 c = lcnt[t];
        lbase[t] = c ? atomicAdd(&cur[s * B + t], c) : 0u;
        lcnt[t] = 0;
    }
    __syncthreads();
#pragma unroll
    for (int k = 0; k < SCHUNK / 256; ++k) {
        const int e = base_e + k * 256 + t;
        if (e < E) {
            const int b = rows[e] >> NB_SHIFT;
            const u32 pos = lbase[b] + atomicAdd(&lcnt[b], 1u);
            mylist[pos] = (u32)e;
        }
    }
}

// ---------------- edge MLP (+ inline global MLP in wave 0) ----------------
// One edge per thread (R4 shape: VGPR ~28, full occupancy at E/256 blocks).

template <bool SKIP, bool GAGG, bool VALS, bool STORE, bool GCOMP>
__global__ __launch_bounds__(256) void edge_kernel(
    const float4* __restrict__ xf,       // node features (N,8) as float4 pairs
    const int* __restrict__ rows, const int* __restrict__ cols,
    const float* __restrict__ eprev,     // previous edge embedding (E)
    const float* __restrict__ skipattr,  // original attr (skip col), if SKIP
    const float* __restrict__ W1,        // 26x32 slice (row-major k,j)
    const float* __restrict__ b1,        // 32
    const float* __restrict__ W2,        // 32
    const float* __restrict__ b2,        // 1
    const float* __restrict__ gprev,     // gslot[j-1] (GCOMP) / gslot[0]=0
    float* __restrict__ gout,            // gslot[j] (GCOMP: block0 writes)
    const float* __restrict__ pebins,    // prev region e-mean bins (GCOMP)
    const float* __restrict__ pnbins,    // prev region n-mean bins (GCOMP)
    const float* __restrict__ gW1, const float* __restrict__ gb1,
    const float* __restrict__ gW2, const float* __restrict__ gb2,
    float* __restrict__ ebins,           // this region's e-mean bins (GAGG)
    float* __restrict__ e_out,           // edge emb store (STORE)
    float* __restrict__ vals_out,        // final output segment (VALS)
    int E, int N, float inv_E) {
    __shared__ float gsh[8];
    __shared__ float biasE[32];
    __shared__ float wpart[4];
    const int t = threadIdx.x;
    if constexpr (GCOMP) {
        if (t < 64) {  // wave 0: g = gMLP(n_mean, e_mean, g_prev)
            float nb[8];
#pragma unroll
            for (int q = 0; q < 8; ++q) nb[q] = pnbins[t * 16 + q];
            const float eb = pebins[t];
            float gin[17];
#pragma unroll
            for (int q = 0; q < 8; ++q) {
                const float s = wave_sum(nb[q]);
                gin[q] = __shfl(s, 0, 64) / (float)N;
            }
            const float es = wave_sum(eb);
            gin[8] = __shfl(es, 0, 64) * inv_E;
#pragma unroll
            for (int k = 0; k < 8; ++k) gin[9 + k] = gprev[k];
            float hv = 0.0f;
            if (t < 32) {
                hv = gb1[t];
#pragma unroll
                for (int k = 0; k < 17; ++k)
                    hv = fmaf(gin[k], gW1[k * 32 + t], hv);
                hv = fmaxf(hv, 0.0f);
            }
#pragma unroll
            for (int q = 0; q < 8; ++q) {
                const float c = (t < 32) ? hv * gW2[t * 8 + q] : 0.0f;
                const float s = wave_sum(c);
                if (t == 0) {
                    const float gv = gb2[q] + s;
                    gsh[q] = gv;
                    if (blockIdx.x == 0) gout[q] = gv;
                }
            }
        }
    } else {
        if (t < 8) gsh[t] = gprev[t];
    }
    __syncthreads();
    if (t < 32) {
        // fold uniform global contribution + b1 into per-pass bias
        float v = b1[t];
#pragma unroll
        for (int k = 0; k < 8; ++k) v = fmaf(gsh[k], W1[k * 32 + t], v);
        biasE[t] = v;
    }
    __syncthreads();

    const int e = blockIdx.x * 256 + t;
    const bool valid = e < E;
    const int idx = valid ? e : 0;
    const int r = rows[idx];
    const int c = cols[idx];
    const float4 xr0 = xf[2 * r], xr1 = xf[2 * r + 1];
    const float4 xc0 = xf[2 * c], xc1 = xf[2 * c + 1];
    float in[18] = {xr0.x, xr0.y, xr0.z, xr0.w, xr1.x, xr1.y, xr1.z, xr1.w,
                    xc0.x, xc0.y, xc0.z, xc0.w, xc1.x, xc1.y, xc1.z, xc1.w,
                    eprev[idx], 0.0f};
    if constexpr (SKIP) in[17] = skipattr[idx];
    float h[32];
#pragma unroll
    for (int j = 0; j < 8; ++j) {
        const float4 b = reinterpret_cast<const float4*>(biasE)[j];
        h[4 * j + 0] = b.x; h[4 * j + 1] = b.y;
        h[4 * j + 2] = b.z; h[4 * j + 3] = b.w;
    }
    const float* __restrict__ Wk = W1 + 8 * 32;  // rows 8..25
#pragma unroll
    for (int k = 0; k < 18; ++k) {
        const float v = in[k];
#pragma unroll
        for (int j = 0; j < 32; ++j) h[j] = fmaf(v, Wk[k * 32 + j], h[j]);
    }
    float out = b2[0];
#pragma unroll
    for (int j = 0; j < 32; ++j) out = fmaf(fmaxf(h[j], 0.0f), W2[j], out);

    if (valid) {
        if constexpr (STORE) e_out[e] = out;
        if constexpr (VALS) vals_out[e] = (r == c) ? expf(out) : out;
    }
    if constexpr (GAGG) {
        const float s = wave_sum(valid ? out : 0.0f);
        if ((t & 63) == 0) wpart[t >> 6] = s;
        __syncthreads();
        if (t == 0)
            atomicAdd(&ebins[blockIdx.x & 63],
                      wpart[0] + wpart[1] + wpart[2] + wpart[3]);
    }
}

// ------- fused aggregation + node MLP: one block owns one bucket -------

template <bool COUNT, bool STORE_N>
__global__ __launch_bounds__(1024) void aggnode_kernel(
    const u32* __restrict__ list, const u32* __restrict__ offs,
    const int* __restrict__ rows, const float* __restrict__ e_emb,
    const float4* __restrict__ xf,  // node features: x (lower) or l_n (upper)
    float* __restrict__ cntf,       // per-node degree (write if COUNT else read)
    const float* __restrict__ g,    // gslot[j] (materialized)
    const float* __restrict__ nW1, const float* __restrict__ nb1,
    const float* __restrict__ nW2, const float* __restrict__ nb2,
    float* __restrict__ n_out,  // l_n (8N) if STORE_N
    float* __restrict__ nbins,  // 64 x 16 n-mean partial bins
    int N) {
    __shared__ float sbin[NB_SIZE];
    __shared__ float cbin[NB_SIZE];
    __shared__ float biasN[32];
    __shared__ float npart[8][8];
    const int t = threadIdx.x;
    if (t < NB_SIZE) {
        sbin[t] = 0.0f;
        if constexpr (COUNT) cbin[t] = 0.0f;
    }
    if (t >= NB_SIZE && t < NB_SIZE + 32) {
        const int j = t - NB_SIZE;
        float v = nb1[j];
#pragma unroll
        for (int k = 0; k < 8; ++k) v = fmaf(g[k], nW1[k * 32 + j], v);
        biasN[j] = v;
    }
    __syncthreads();
    const int b = blockIdx.x;
    const u32 beg = offs[b], end = offs[b + 1];
    for (u32 i = beg + t; i < end; i += 1024) {
        const u32 eid = list[i];
        const float v = e_emb[eid];
        const int r = rows[eid];
        atomicAdd(&sbin[r & (NB_SIZE - 1)], v);
        if constexpr (COUNT) atomicAdd(&cbin[r & (NB_SIZE - 1)], 1.0f);
    }
    __syncthreads();

    const int n0 = b << NB_SHIFT;
    float o[8];
    const bool active = (t < NB_SIZE) && (n0 + t < N);
    if (t < NB_SIZE) {
        const int n = n0 + t;
        const int idx = active ? n : (N - 1);
        float cntv;
        if constexpr (COUNT) {
            cntv = cbin[t];
            if (active) cntf[n] = cntv;
        } else {
            cntv = cntf[idx];
        }
        const float agg = sbin[t] / fmaxf(cntv, 1.0f);
        const float4 x0 = xf[2 * idx], x1 = xf[2 * idx + 1];
        float in[9] = {x0.x, x0.y, x0.z, x0.w, x1.x, x1.y, x1.z, x1.w, agg};
        float h[32];
#pragma unroll
        for (int j = 0; j < 8; ++j) {
            const float4 bb = reinterpret_cast<const float4*>(biasN)[j];
            h[4 * j + 0] = bb.x; h[4 * j + 1] = bb.y;
            h[4 * j + 2] = bb.z; h[4 * j + 3] = bb.w;
        }
        const float* __restrict__ Wk = nW1 + 8 * 32;
#pragma unroll
        for (int k = 0; k < 9; ++k) {
            const float v = in[k];
#pragma unroll
            for (int j = 0; j < 32; ++j) h[j] = fmaf(v, Wk[k * 32 + j], h[j]);
        }
#pragma unroll
        for (int q = 0; q < 8; ++q) o[q] = nb2[q];
#pragma unroll
        for (int j = 0; j < 32; ++j) {
            const float hv = fmaxf(h[j], 0.0f);
#pragma unroll
            for (int q = 0; q < 8; ++q) o[q] = fmaf(hv, nW2[j * 8 + q], o[q]);
        }
        if constexpr (STORE_N) {
            if (active) {
                reinterpret_cast<float4*>(n_out)[2 * n] =
                    make_float4(o[0], o[1], o[2], o[3]);
                reinterpret_cast<float4*>(n_out)[2 * n + 1] =
                    make_float4(o[4], o[5], o[6], o[7]);
            }
        }
#pragma unroll
        for (int q = 0; q < 8; ++q) {
            const float s = wave_sum(active ? o[q] : 0.0f);
            if ((t & 63) == 0) npart[t >> 6][q] = s;
        }
    }
    __syncthreads();
    if (t < 8) {
        float a = 0.0f;
#pragma unroll
        for (int w = 0; w < 8; ++w) a += npart[w][t];
        atomicAdd(&nbins[(b & 63) * 16 + t], a);
    }
}

extern "C" void kernel_launch(void* const* d_in, const int* in_sizes, int n_in,
                              void* d_out, int out_size, void* d_ws,
                              size_t ws_size, hipStream_t stream) {
    const float* x = (const float*)d_in[0];
    const int* l_ei = (const int*)d_in[1];
    const int* u_ei = (const int*)d_in[2];
    const float* l_attr = (const float*)d_in[3];
    const float* u_attr = (const float*)d_in[4];
    const float* eW1 = (const float*)d_in[5];
    const float* eb1 = (const float*)d_in[6];
    const float* eW2 = (const float*)d_in[7];
    const float* eb2 = (const float*)d_in[8];
    const float* nW1 = (const float*)d_in[9];
    const float* nb1 = (const float*)d_in[10];
    const float* nW2 = (const float*)d_in[11];
    const float* nb2 = (const float*)d_in[12];
    const float* gW1 = (const float*)d_in[13];
    const float* gb1 = (const float*)d_in[14];
    const float* gW2 = (const float*)d_in[15];
    const float* gb2 = (const float*)d_in[16];

    const int E = in_sizes[3];      // 1,100,000
    const int N = in_sizes[0] / 8;  // 100,000
    const int B = (N + NB_SIZE - 1) >> NB_SHIFT;  // 196 buckets

    // workspace layout (floats)
    float* ws = (float*)d_ws;
    float* l_e = ws;                      // E
    float* u_e = l_e + E;                 // E
    float* l_n = u_e + E;                 // 8N (float4-aligned)
    float* cnt_l = l_n + (size_t)8 * N;   // N (float degree)
    float* cnt_u = cnt_l + N;             // N
    float* gslot = cnt_u + N;             // 7 x 8 (slot j = g used by GNet j)
    u32* hist = (u32*)(gslot + 56);       // 2B
    float* dyn_all = (float*)(hist + 2 * B);    // 5 * RSTRIDE
    u32* offs = (u32*)(dyn_all + 5 * RSTRIDE);  // 2(B+1)
    u32* cur = offs + 2 * (B + 1);        // 2B
    u32* list = cur + 2 * B;              // 2E (lower | upper)

    const int* lr = l_ei;
    const int* lc = l_ei + E;
    const int* ur = u_ei;
    const int* uc = u_ei + E;
    const int eg = (E + 255) / 256;
    const int sg = (E + SCHUNK - 1) / SCHUNK;
    const float invE = 1.0f / (float)E;
    float* outL = (float*)d_out;
    float* outU = outL + E;
    const u32* offs_l = offs;
    const u32* offs_u = offs + (B + 1);
    const u32* list_l = list;
    const u32* list_u = list + E;

    // one memset: gslots + hist + all 5 bin regions
    hipMemsetAsync(gslot, 0, (size_t)(56 + 2 * B + 5 * RSTRIDE) * sizeof(float),
                   stream);
    hist_kernel<<<dim3(128, 2), 256, 0, stream>>>(lr, ur, hist, E, B);
    scan_kernel<<<1, 256, 0, stream>>>(hist, offs, cur, B);
    scatter_kernel<<<dim3(sg, 2), 256, 0, stream>>>(lr, ur, cur, list, E, B);

    // weight-slice per GraphNet j: lower i -> i, upper i -> 3+i
    const size_t wsl[6] = {0, 3, 1, 4, 2, 5};

    for (int j = 0; j < 6; ++j) {
        const bool lower = !(j & 1);
        const size_t sl = wsl[j];
        float* ebins = dyn_all + (size_t)(j <= 4 ? j : 4) * RSTRIDE;
        float* nbins = ebins + 64;
        const float* pe = (j >= 1) ? dyn_all + (size_t)(j - 1) * RSTRIDE : nullptr;
        const float* pn = (j >= 1) ? pe + 64 : nullptr;
        const size_t psl = (j >= 1) ? wsl[j - 1] : 0;
        const float4* exf = (const float4*)(lower ? x : l_n);
        const int* rows = lower ? lr : ur;
        const int* cols = lower ? lc : uc;
        const float* eprev = (j == 0) ? l_attr
                             : (j == 1) ? u_attr
                             : (lower ? l_e : u_e);
        float* e_out = lower ? l_e : u_e;
        const float* gprev = gslot + (size_t)(j >= 1 ? j - 1 : 0) * 8;
        float* gout = gslot + (size_t)j * 8;

#define EDGE_ARGS                                                             \
    exf, rows, cols, eprev, l_attr, eW1 + sl * 832, eb1 + sl * 32,            \
        eW2 + sl * 32, eb2 + sl, gprev, gout, pe, pn, gW1 + psl * 544,        \
        gb1 + psl * 32, gW2 + psl * 256, gb2 + psl * 8, ebins,                \
        e_out, (j == 4) ? outL : outU, E, N, invE

        switch (j) {  // SKIP, GAGG, VALS, STORE, GCOMP
            case 0: edge_kernel<false, true, false, true, false>
                        <<<eg, 256, 0, stream>>>(EDGE_ARGS); break;
            case 1: edge_kernel<false, true, false, true, true>
                        <<<eg, 256, 0, stream>>>(EDGE_ARGS); break;
            case 2: edge_kernel<true, true, false, true, true>
                        <<<eg, 256, 0, stream>>>(EDGE_ARGS); break;
            case 3: edge_kernel<false, true, false, true, true>
                        <<<eg, 256, 0, stream>>>(EDGE_ARGS); break;
            case 4: edge_kernel<true, true, true, true, true>
                        <<<eg, 256, 0, stream>>>(EDGE_ARGS); break;
            case 5: edge_kernel<false, false, true, false, true>
                        <<<eg, 256, 0, stream>>>(EDGE_ARGS); break;
        }
#undef EDGE_ARGS

        if (j == 5) break;  // final upper GraphNet: edge output only

        const u32* alist = lower ? list_l : list_u;
        const u32* aoffs = lower ? offs_l : offs_u;
        float* cntf = lower ? cnt_l : cnt_u;
        const float4* nxf = (const float4*)(lower ? x : l_n);

#define AGG_ARGS                                                              \
    alist, aoffs, rows, e_out, nxf, cntf, gslot + (size_t)j * 8,              \
        nW1 + sl * 544, nb1 + sl * 32, nW2 + sl * 256, nb2 + sl * 8, l_n,     \
        nbins, N

        switch (j) {  // COUNT, STORE_N
            case 0: aggnode_kernel<true, true>
                        <<<B, 1024, 0, stream>>>(AGG_ARGS); break;
            case 1: aggnode_kernel<true, false>
                        <<<B, 1024, 0, stream>>>(AGG_ARGS); break;
            case 2: aggnode_kernel<false, true>
                        <<<B, 1024, 0, stream>>>(AGG_ARGS); break;
            case 3: aggnode_kernel<false, false>
                        <<<B, 1024, 0, stream>>>(AGG_ARGS); break;
            case 4: aggnode_kernel<false, true>
                        <<<B, 1024, 0, stream>>>(AGG_ARGS); break;
        }
#undef AGG_ARGS
    }
}